// Round 4
// baseline (236.570 us; speedup 1.0000x reference)
//
#include <hip/hip_runtime.h>
#include <hip/hip_bf16.h>

// Problem constants
#define NB    4
#define NP    12          // P1 == P == 12
#define NN_   207
#define DM    128         // d_model
#define DHID  256
#define M_TOK 9936        // NB*NP*NN_
#define M_PADX 9984       // xT row stride (transpose pads to 9984, zero-filled)
#define MTILE 112         // gemm m-tile (7 x 16)
#define MBLK  89          // ceil(9936/112)
#define KSPLIT 8          // j-splits (j-chunk = 32)

typedef float        f32x4 __attribute__((ext_vector_type(4)));
typedef unsigned int u32x4 __attribute__((ext_vector_type(4)));
typedef __bf16       bf16x8 __attribute__((ext_vector_type(8)));

static __device__ __forceinline__ unsigned int pk_bf2(float a, float b) {
    __hip_bfloat16 ba = __float2bfloat16(a);
    __hip_bfloat16 bb = __float2bfloat16(b);
    unsigned short ua = *reinterpret_cast<unsigned short*>(&ba);
    unsigned short ub = *reinterpret_cast<unsigned short*>(&bb);
    return (unsigned int)ua | ((unsigned int)ub << 16);
}

// ---------------- fused prep kernel: W2->bf16 | transpose x | meta (h, Qb) ----------
// blocks [0,2048): cvt_w2; [2048,3296): transpose; [3296,4538): meta
__global__ __launch_bounds__(256) void k_prep(const float* __restrict__ W2,
                                              unsigned short* __restrict__ W2b,
                                              const float* __restrict__ x,
                                              float* __restrict__ xT,
                                              const float* __restrict__ ct,
                                              const float* __restrict__ W1,
                                              const float* __restrict__ b1,
                                              const float* __restrict__ b2,
                                              float* __restrict__ hbuf,
                                              float* __restrict__ Qb) {
    __shared__ float sm[2112];
    const int t = threadIdx.x;
    const int bid = blockIdx.x;
    if (bid < 2048) {
        // ---- W2 fp32 -> bf16, 8 f32 per thread ----
        int i = bid * 256 + t;
        const f32x4* in = reinterpret_cast<const f32x4*>(W2);
        f32x4 v0 = in[2 * i], v1 = in[2 * i + 1];
        u32x4 o;
        o[0] = pk_bf2(v0[0], v0[1]);
        o[1] = pk_bf2(v0[2], v0[3]);
        o[2] = pk_bf2(v1[0], v1[1]);
        o[3] = pk_bf2(v1[2], v1[3]);
        reinterpret_cast<u32x4*>(W2b)[i] = o;
    } else if (bid < 3296) {
        // ---- transpose inputs -> xT[128][M_PADX], pad m>=M_TOK with 0 ----
        float (*tile)[33] = reinterpret_cast<float (*)[33]>(sm);
        const int b = bid - 2048;
        const int bm = b >> 2;          // 312 m-tiles of 32
        const int bd = b & 3;           // 4 d-tiles of 32
        const int m0 = bm * 32, d0 = bd * 32;
        #pragma unroll
        for (int i = 0; i < 4; ++i) {
            int e = i * 256 + t;
            int lm = e >> 5, ld = e & 31;
            int m = m0 + lm;
            tile[lm][ld] = (m < M_TOK) ? x[(size_t)m * DM + d0 + ld] : 0.0f;
        }
        __syncthreads();
        #pragma unroll
        for (int i = 0; i < 4; ++i) {
            int e = i * 256 + t;
            int ld = e >> 5, lm = e & 31;
            xT[(size_t)(d0 + ld) * M_PADX + m0 + lm] = tile[lm][ld];
        }
    } else {
        // ---- meta: h = relu(W1 ct + b1); Qb = b2-reshaped . x ----
        float* cts = sm;                // [8][128]
        float* xs  = sm + 1024;         // [8][128]
        const int b = bid - 3296;
        const int m0 = b * 8;
        {
            int tok = t >> 5, c4 = t & 31;
            *reinterpret_cast<f32x4*>(&cts[tok * 128 + c4 * 4]) =
                *reinterpret_cast<const f32x4*>(&ct[(size_t)(m0 + tok) * DM + c4 * 4]);
            *reinterpret_cast<f32x4*>(&xs[tok * 128 + c4 * 4]) =
                *reinterpret_cast<const f32x4*>(&x[(size_t)(m0 + tok) * DM + c4 * 4]);
        }
        __syncthreads();
        {   // h: thread t owns hidden unit j = t for 8 tokens
            const int j = t;
            const f32x4* w1r = reinterpret_cast<const f32x4*>(&W1[(size_t)j * DM]);
            float acc[8] = {0, 0, 0, 0, 0, 0, 0, 0};
            for (int c = 0; c < 32; ++c) {
                f32x4 wv = w1r[c];
                #pragma unroll
                for (int tok = 0; tok < 8; ++tok) {
                    f32x4 cv = *reinterpret_cast<const f32x4*>(&cts[tok * 128 + c * 4]);
                    acc[tok] += wv[0] * cv[0] + wv[1] * cv[1] + wv[2] * cv[2] + wv[3] * cv[3];
                }
            }
            float bb = b1[j];
            #pragma unroll
            for (int tok = 0; tok < 8; ++tok)
                hbuf[(size_t)(m0 + tok) * DHID + j] = fmaxf(acc[tok] + bb, 0.0f);
        }
        {   // Qb: thread owns output o = t&127 for 4 tokens
            const int o = t & 127;
            const int tg = (t >> 7) * 4;
            const f32x4* b2r = reinterpret_cast<const f32x4*>(&b2[(size_t)o * DM]);
            float acc[4] = {0, 0, 0, 0};
            for (int c = 0; c < 32; ++c) {
                f32x4 wv = b2r[c];
                #pragma unroll
                for (int tt = 0; tt < 4; ++tt) {
                    f32x4 xv = *reinterpret_cast<const f32x4*>(&xs[(tg + tt) * 128 + c * 4]);
                    acc[tt] += wv[0] * xv[0] + wv[1] * xv[1] + wv[2] * xv[2] + wv[3] * xv[3];
                }
            }
            #pragma unroll
            for (int tt = 0; tt < 4; ++tt)
                Qb[(size_t)(m0 + tg + tt) * DM + o] = acc[tt];
        }
    }
}

// ---------------- kernel: bilinear GEMM, LDS-free / barrier-free ----------------
// Q[m,o] = sum_{d,j} bf16(x[m,d]*h[m,j]) * bf16(W2[o*128+d, j0+j])
// h-fragments live in VGPRs (constant over d); A built in-register each step via
// MFMA *intrinsic* (compiler handles VALU<->MFMA hazards; inline asm did NOT — r3 NaN).
// B-fragments loaded straight from global (per-XCD-L2-resident 1MB slice) with
// 1-deep register prefetch. No __shared__, no __syncthreads.
__global__ __launch_bounds__(256, 3) void k_gemm(const unsigned short* __restrict__ W2b,
                                                 const float* __restrict__ hbuf,
                                                 const float* __restrict__ xT,
                                                 float* __restrict__ Qp) {
    const int t = threadIdx.x;
    const int kid = blockIdx.x & 7;      // j-split -> XCD (round-robin dispatch)
    const int mb  = blockIdx.x >> 3;     // 0..88
    const int m0 = mb * MTILE;
    const int j0 = kid * 32;
    const int w  = t >> 6;               // wave 0..3 owns o-range w*32
    const int l  = t & 63;
    const int lr = l & 15;               // fragment row/col
    const int g  = l >> 4;               // k-chunk group
    const int obase = w * 32;

    // h fragments: 7 rows (m0+mt*16+lr), 8 j's (j0+g*8..+7), fp32, 56 VGPRs
    f32x4 hA[7], hB[7];
    #pragma unroll
    for (int mt = 0; mt < 7; ++mt) {
        int m = m0 + mt * 16 + lr;
        if (m < M_TOK) {
            const float* hp = &hbuf[(size_t)m * DHID + j0 + g * 8];
            hA[mt] = *reinterpret_cast<const f32x4*>(hp);
            hB[mt] = *reinterpret_cast<const f32x4*>(hp + 4);
        } else {
            hA[mt] = (f32x4)(0.0f);
            hB[mt] = (f32x4)(0.0f);
        }
    }

    f32x4 acc[7][2];
    #pragma unroll
    for (int mt = 0; mt < 7; ++mt) {
        acc[mt][0] = (f32x4)(0.0f);
        acc[mt][1] = (f32x4)(0.0f);
    }

    // B pointers: rows o*128+d of W2b, 16B at column j0+g*8; advance 256 shorts/d
    const unsigned short* bp0 = W2b + (size_t)(obase + lr) * 32768 + j0 + g * 8;
    const unsigned short* bp1 = W2b + (size_t)(obase + 16 + lr) * 32768 + j0 + g * 8;
    const float* xp = xT + m0 + lr;      // x[m0+mt*16+lr, d]; advance M_PADX/d

    // prefetch d=0
    bf16x8 bn0 = *reinterpret_cast<const bf16x8*>(bp0);
    bf16x8 bn1 = *reinterpret_cast<const bf16x8*>(bp1);
    float xn0 = xp[0],  xn1 = xp[16], xn2 = xp[32], xn3 = xp[48];
    float xn4 = xp[64], xn5 = xp[80], xn6 = xp[96];

    for (int d = 0; d < 128; ++d) {
        const bf16x8 bc0 = bn0, bc1 = bn1;
        float xc[7] = {xn0, xn1, xn2, xn3, xn4, xn5, xn6};
        if (d < 127) {                    // 1-deep register prefetch of d+1
            bp0 += 256; bp1 += 256; xp += M_PADX;
            bn0 = *reinterpret_cast<const bf16x8*>(bp0);
            bn1 = *reinterpret_cast<const bf16x8*>(bp1);
            xn0 = xp[0];  xn1 = xp[16]; xn2 = xp[32]; xn3 = xp[48];
            xn4 = xp[64]; xn5 = xp[80]; xn6 = xp[96];
        }
        __builtin_amdgcn_s_setprio(1);
        #pragma unroll
        for (int mt = 0; mt < 7; ++mt) {
            bf16x8 a;
            a[0] = (__bf16)(xc[mt] * hA[mt][0]);
            a[1] = (__bf16)(xc[mt] * hA[mt][1]);
            a[2] = (__bf16)(xc[mt] * hA[mt][2]);
            a[3] = (__bf16)(xc[mt] * hA[mt][3]);
            a[4] = (__bf16)(xc[mt] * hB[mt][0]);
            a[5] = (__bf16)(xc[mt] * hB[mt][1]);
            a[6] = (__bf16)(xc[mt] * hB[mt][2]);
            a[7] = (__bf16)(xc[mt] * hB[mt][3]);
            acc[mt][0] = __builtin_amdgcn_mfma_f32_16x16x32_bf16(a, bc0, acc[mt][0], 0, 0, 0);
            acc[mt][1] = __builtin_amdgcn_mfma_f32_16x16x32_bf16(a, bc1, acc[mt][1], 0, 0, 0);
        }
        __builtin_amdgcn_s_setprio(0);
    }

    // epilogue: D layout col(o) = lane&15, row(m) = (lane>>4)*4 + reg
    float* outp = Qp + (size_t)kid * M_TOK * DM;
    #pragma unroll
    for (int mt = 0; mt < 7; ++mt)
        #pragma unroll
        for (int r = 0; r < 4; ++r) {
            int m = m0 + mt * 16 + g * 4 + r;
            if (m < M_TOK) {
                float* row = outp + (size_t)m * DM + obase + lr;
                row[0]  = acc[mt][0][r];
                row[16] = acc[mt][1][r];
            }
        }
}

// ---------------- attention + W_out + residual + layernorm ----------------
__global__ __launch_bounds__(256) void k_attn(const float* __restrict__ Qp,
                                              const float* __restrict__ Qb,
                                              const float* __restrict__ Kenc,
                                              const float* __restrict__ Venc,
                                              const float* __restrict__ xin,
                                              const float* __restrict__ Wout,
                                              const float* __restrict__ gamma,
                                              const float* __restrict__ beta,
                                              float* __restrict__ out) {
    __shared__ float Qs[12][132];
    __shared__ float Ks[12][132];
    __shared__ float Vs[12][132];
    __shared__ float Ss[12][12][8];
    __shared__ float Os[12][132];
    __shared__ float Ws[64][132];
    const int t = threadIdx.x;
    const int b = blockIdx.x / NN_;
    const int n = blockIdx.x % NN_;

    for (int e = t; e < 384; e += 256) {
        int row = e >> 5, c4 = e & 31;
        size_t mrow = (size_t)(b * NP + row) * NN_ + n;
        f32x4 q = *reinterpret_cast<const f32x4*>(&Qb[mrow * DM + c4 * 4]);
        #pragma unroll
        for (int k = 0; k < KSPLIT; ++k)
            q += *reinterpret_cast<const f32x4*>(&Qp[((size_t)k * M_TOK + mrow) * DM + c4 * 4]);
        *reinterpret_cast<f32x4*>(&Qs[row][c4 * 4]) = q;
        *reinterpret_cast<f32x4*>(&Ks[row][c4 * 4]) =
            *reinterpret_cast<const f32x4*>(&Kenc[mrow * DM + c4 * 4]);
        *reinterpret_cast<f32x4*>(&Vs[row][c4 * 4]) =
            *reinterpret_cast<const f32x4*>(&Venc[mrow * DM + c4 * 4]);
    }
    __syncthreads();
    if (t < 144) {
        int q = t / 12, p = t % 12;
        #pragma unroll
        for (int hh = 0; hh < 8; ++hh) {
            const f32x4* qv = reinterpret_cast<const f32x4*>(&Qs[q][hh * 16]);
            const f32x4* kv = reinterpret_cast<const f32x4*>(&Ks[p][hh * 16]);
            float s = 0.0f;
            #pragma unroll
            for (int c = 0; c < 4; ++c) {
                f32x4 a = qv[c], bb = kv[c];
                s += a[0] * bb[0] + a[1] * bb[1] + a[2] * bb[2] + a[3] * bb[3];
            }
            Ss[q][p][hh] = s * 0.25f;
        }
    }
    __syncthreads();
    if (t < 96) {
        int q = t >> 3, hh = t & 7;
        float mx = -1e30f;
        #pragma unroll
        for (int p = 0; p < 12; ++p) mx = fmaxf(mx, Ss[q][p][hh]);
        float ev[12]; float sum = 0.0f;
        #pragma unroll
        for (int p = 0; p < 12; ++p) { ev[p] = __expf(Ss[q][p][hh] - mx); sum += ev[p]; }
        float inv = 1.0f / sum;
        #pragma unroll
        for (int p = 0; p < 12; ++p) Ss[q][p][hh] = ev[p] * inv;
    }
    __syncthreads();
    #pragma unroll
    for (int i = 0; i < 6; ++i) {
        int e = i * 256 + t;
        int q = e >> 7, hk = e & 127, hh = hk >> 4;
        float acc = 0.0f;
        #pragma unroll
        for (int p = 0; p < 12; ++p) acc += Ss[q][p][hh] * Vs[p][hk];
        Os[q][hk] = acc;
    }
    __syncthreads();
    for (int half = 0; half < 2; ++half) {
        #pragma unroll
        for (int i = 0; i < 8; ++i) {
            int e = i * 256 + t;
            int row = e >> 5, c4 = e & 31;
            *reinterpret_cast<f32x4*>(&Ws[row][c4 * 4]) =
                *reinterpret_cast<const f32x4*>(&Wout[(size_t)(half * 64 + row) * DM + c4 * 4]);
        }
        __syncthreads();
        #pragma unroll
        for (int i = 0; i < 3; ++i) {
            int idx = i * 256 + t;
            int o = idx / 12, q = idx % 12;
            const f32x4* ov = reinterpret_cast<const f32x4*>(&Os[q][0]);
            const f32x4* wv = reinterpret_cast<const f32x4*>(&Ws[o][0]);
            float s = 0.0f;
            #pragma unroll
            for (int c = 0; c < 32; ++c) {
                f32x4 a = ov[c], bb = wv[c];
                s += a[0] * bb[0] + a[1] * bb[1] + a[2] * bb[2] + a[3] * bb[3];
            }
            int oo = half * 64 + o;
            size_t mrow = (size_t)(b * NP + q) * NN_ + n;
            Qs[q][oo] = s + xin[mrow * DM + oo];
        }
        __syncthreads();
    }
    const int wv_ = t >> 6, l = t & 63;
    for (int rq = wv_; rq < 12; rq += 4) {
        float v0 = Qs[rq][l], v1 = Qs[rq][l + 64];
        float s = v0 + v1, ss = v0 * v0 + v1 * v1;
        #pragma unroll
        for (int msk = 1; msk < 64; msk <<= 1) {
            s += __shfl_xor(s, msk, 64);
            ss += __shfl_xor(ss, msk, 64);
        }
        float mu = s * (1.0f / 128.0f);
        float var = ss * (1.0f / 128.0f) - mu * mu;
        float rs = rsqrtf(var + 1e-5f);
        size_t mrow = (size_t)(b * NP + rq) * NN_ + n;
        out[mrow * DM + l]      = (v0 - mu) * rs * gamma[l] + beta[l];
        out[mrow * DM + l + 64] = (v1 - mu) * rs * gamma[l + 64] + beta[l + 64];
    }
}

// ---------------- launcher ----------------
extern "C" void kernel_launch(void* const* d_in, const int* in_sizes, int n_in,
                              void* d_out, int out_size, void* d_ws, size_t ws_size,
                              hipStream_t stream) {
    const float* xin   = (const float*)d_in[0];
    const float* Kenc  = (const float*)d_in[1];
    const float* Venc  = (const float*)d_in[2];
    const float* ct    = (const float*)d_in[3];
    const float* W1    = (const float*)d_in[4];
    const float* b1    = (const float*)d_in[5];
    const float* W2    = (const float*)d_in[6];
    const float* b2    = (const float*)d_in[7];
    const float* Wout  = (const float*)d_in[8];
    const float* gamma = (const float*)d_in[9];
    const float* beta  = (const float*)d_in[10];
    float* out = (float*)d_out;

    char* ws = (char*)d_ws;
    unsigned short* W2b = (unsigned short*)(ws);                  //  8,388,608 B
    float* xT  = (float*)(ws + 8388608);                          //  5,111,808 B (128 x 9984)
    float* hb  = (float*)(ws + 13500416);                         // 10,174,464 B used
    float* Qb  = (float*)(ws + 23724032);                         //  5,087,232 B used
    float* Qp  = (float*)(ws + 28835840);                         // 40,697,856 B (8 x 9936 x 128)

    hipLaunchKernelGGL(k_prep, dim3(4538), dim3(256), 0, stream,
                       W2, W2b, xin, xT, ct, W1, b1, b2, hb, Qb);
    hipLaunchKernelGGL(k_gemm, dim3(MBLK * KSPLIT), dim3(256), 0, stream, W2b, hb, xT, Qp);
    hipLaunchKernelGGL(k_attn, dim3(828), dim3(256), 0, stream, Qp, Qb, Kenc, Venc,
                       xin, Wout, gamma, beta, out);
}

// Round 5
// 232.973 us; speedup vs baseline: 1.0154x; 1.0154x over previous
//
#include <hip/hip_runtime.h>
#include <hip/hip_bf16.h>

// Problem constants
#define NB    4
#define NP    12          // P1 == P == 12
#define NN_   207
#define DM    128         // d_model
#define DHID  256
#define M_TOK 9936        // NB*NP*NN_
#define M_PADX 9984       // xT row stride (transpose pads to 9984, zero-filled)
#define MTILE 112         // gemm m-tile (7 x 16)
#define MBLK  89          // ceil(9936/112)
#define KSPLIT 8          // j-splits (j-chunk = 32)

typedef float        f32x4 __attribute__((ext_vector_type(4)));
typedef unsigned int u32x4 __attribute__((ext_vector_type(4)));
typedef __bf16       bf16x8 __attribute__((ext_vector_type(8)));

static __device__ __forceinline__ unsigned int pk_bf2(float a, float b) {
    __hip_bfloat16 ba = __float2bfloat16(a);
    __hip_bfloat16 bb = __float2bfloat16(b);
    unsigned short ua = *reinterpret_cast<unsigned short*>(&ba);
    unsigned short ub = *reinterpret_cast<unsigned short*>(&bb);
    return (unsigned int)ua | ((unsigned int)ub << 16);
}

// hardware packed f32->bf16 (RNE), 1 instr per 2 elements; no builtin on gfx950
static __device__ __forceinline__ unsigned int cvt_pk_bf16(float lo, float hi) {
    unsigned int r;
    asm("v_cvt_pk_bf16_f32 %0, %1, %2" : "=v"(r) : "v"(lo), "v"(hi));
    return r;
}

// ---------------- fused prep kernel: W2->bf16 | transpose x | meta (h, Qb) ----------
// blocks [0,2048): cvt_w2; [2048,3296): transpose; [3296,4538): meta
__global__ __launch_bounds__(256) void k_prep(const float* __restrict__ W2,
                                              unsigned short* __restrict__ W2b,
                                              const float* __restrict__ x,
                                              float* __restrict__ xT,
                                              const float* __restrict__ ct,
                                              const float* __restrict__ W1,
                                              const float* __restrict__ b1,
                                              const float* __restrict__ b2,
                                              float* __restrict__ hbuf,
                                              float* __restrict__ Qb) {
    __shared__ float sm[2112];
    const int t = threadIdx.x;
    const int bid = blockIdx.x;
    if (bid < 2048) {
        // ---- W2 fp32 -> bf16, 8 f32 per thread ----
        int i = bid * 256 + t;
        const f32x4* in = reinterpret_cast<const f32x4*>(W2);
        f32x4 v0 = in[2 * i], v1 = in[2 * i + 1];
        u32x4 o;
        o[0] = pk_bf2(v0[0], v0[1]);
        o[1] = pk_bf2(v0[2], v0[3]);
        o[2] = pk_bf2(v1[0], v1[1]);
        o[3] = pk_bf2(v1[2], v1[3]);
        reinterpret_cast<u32x4*>(W2b)[i] = o;
    } else if (bid < 3296) {
        // ---- transpose inputs -> xT[128][M_PADX], pad m>=M_TOK with 0 ----
        float (*tile)[33] = reinterpret_cast<float (*)[33]>(sm);
        const int b = bid - 2048;
        const int bm = b >> 2;          // 312 m-tiles of 32
        const int bd = b & 3;           // 4 d-tiles of 32
        const int m0 = bm * 32, d0 = bd * 32;
        #pragma unroll
        for (int i = 0; i < 4; ++i) {
            int e = i * 256 + t;
            int lm = e >> 5, ld = e & 31;
            int m = m0 + lm;
            tile[lm][ld] = (m < M_TOK) ? x[(size_t)m * DM + d0 + ld] : 0.0f;
        }
        __syncthreads();
        #pragma unroll
        for (int i = 0; i < 4; ++i) {
            int e = i * 256 + t;
            int ld = e >> 5, lm = e & 31;
            xT[(size_t)(d0 + ld) * M_PADX + m0 + lm] = tile[lm][ld];
        }
    } else {
        // ---- meta: h = relu(W1 ct + b1); Qb = b2-reshaped . x ----
        float* cts = sm;                // [8][128]
        float* xs  = sm + 1024;         // [8][128]
        const int b = bid - 3296;
        const int m0 = b * 8;
        {
            int tok = t >> 5, c4 = t & 31;
            *reinterpret_cast<f32x4*>(&cts[tok * 128 + c4 * 4]) =
                *reinterpret_cast<const f32x4*>(&ct[(size_t)(m0 + tok) * DM + c4 * 4]);
            *reinterpret_cast<f32x4*>(&xs[tok * 128 + c4 * 4]) =
                *reinterpret_cast<const f32x4*>(&x[(size_t)(m0 + tok) * DM + c4 * 4]);
        }
        __syncthreads();
        {   // h: thread t owns hidden unit j = t for 8 tokens
            const int j = t;
            const f32x4* w1r = reinterpret_cast<const f32x4*>(&W1[(size_t)j * DM]);
            float acc[8] = {0, 0, 0, 0, 0, 0, 0, 0};
            for (int c = 0; c < 32; ++c) {
                f32x4 wv = w1r[c];
                #pragma unroll
                for (int tok = 0; tok < 8; ++tok) {
                    f32x4 cv = *reinterpret_cast<const f32x4*>(&cts[tok * 128 + c * 4]);
                    acc[tok] += wv[0] * cv[0] + wv[1] * cv[1] + wv[2] * cv[2] + wv[3] * cv[3];
                }
            }
            float bb = b1[j];
            #pragma unroll
            for (int tok = 0; tok < 8; ++tok)
                hbuf[(size_t)(m0 + tok) * DHID + j] = fmaxf(acc[tok] + bb, 0.0f);
        }
        {   // Qb: thread owns output o = t&127 for 4 tokens
            const int o = t & 127;
            const int tg = (t >> 7) * 4;
            const f32x4* b2r = reinterpret_cast<const f32x4*>(&b2[(size_t)o * DM]);
            float acc[4] = {0, 0, 0, 0};
            for (int c = 0; c < 32; ++c) {
                f32x4 wv = b2r[c];
                #pragma unroll
                for (int tt = 0; tt < 4; ++tt) {
                    f32x4 xv = *reinterpret_cast<const f32x4*>(&xs[(tg + tt) * 128 + c * 4]);
                    acc[tt] += wv[0] * xv[0] + wv[1] * xv[1] + wv[2] * xv[2] + wv[3] * xv[3];
                }
            }
            #pragma unroll
            for (int tt = 0; tt < 4; ++tt)
                Qb[(size_t)(m0 + tg + tt) * DM + o] = acc[tt];
        }
    }
}

// ---------------- kernel: bilinear GEMM, LDS-free / barrier-free ----------------
// Q[m,o] = sum_{d,j} bf16(x[m,d]*h[m,j]) * bf16(W2[o*128+d, j0+j])
// h-fragments live in VGPRs (constant over d); A built in-register each step via
// scalar muls + v_cvt_pk_bf16_f32 (HW packed RNE converter); MFMA via intrinsic
// (compiler handles VALU<->MFMA hazards — inline-asm MFMA NaN'd in r3).
// B-fragments loaded straight from global (per-XCD-L2-resident 1MB slice) with
// 1-deep register prefetch. No __shared__, no __syncthreads.
__global__ __launch_bounds__(256, 3) void k_gemm(const unsigned short* __restrict__ W2b,
                                                 const float* __restrict__ hbuf,
                                                 const float* __restrict__ xT,
                                                 float* __restrict__ Qp) {
    const int t = threadIdx.x;
    const int kid = blockIdx.x & 7;      // j-split -> XCD (round-robin dispatch)
    const int mb  = blockIdx.x >> 3;     // 0..88
    const int m0 = mb * MTILE;
    const int j0 = kid * 32;
    const int w  = t >> 6;               // wave 0..3 owns o-range w*32
    const int l  = t & 63;
    const int lr = l & 15;               // fragment row/col
    const int g  = l >> 4;               // k-chunk group
    const int obase = w * 32;

    // h fragments: 7 rows (m0+mt*16+lr), 8 j's (j0+g*8..+7), fp32, 56 VGPRs
    f32x4 hA[7], hB[7];
    #pragma unroll
    for (int mt = 0; mt < 7; ++mt) {
        int m = m0 + mt * 16 + lr;
        if (m < M_TOK) {
            const float* hp = &hbuf[(size_t)m * DHID + j0 + g * 8];
            hA[mt] = *reinterpret_cast<const f32x4*>(hp);
            hB[mt] = *reinterpret_cast<const f32x4*>(hp + 4);
        } else {
            hA[mt] = (f32x4)(0.0f);
            hB[mt] = (f32x4)(0.0f);
        }
    }

    f32x4 acc[7][2];
    #pragma unroll
    for (int mt = 0; mt < 7; ++mt) {
        acc[mt][0] = (f32x4)(0.0f);
        acc[mt][1] = (f32x4)(0.0f);
    }

    // B pointers: rows o*128+d of W2b, 16B at column j0+g*8; advance 256 shorts/d
    const unsigned short* bp0 = W2b + (size_t)(obase + lr) * 32768 + j0 + g * 8;
    const unsigned short* bp1 = W2b + (size_t)(obase + 16 + lr) * 32768 + j0 + g * 8;
    const float* xp = xT + m0 + lr;      // x[m0+mt*16+lr, d]; advance M_PADX/d

    // prefetch d=0
    bf16x8 bn0 = *reinterpret_cast<const bf16x8*>(bp0);
    bf16x8 bn1 = *reinterpret_cast<const bf16x8*>(bp1);
    float xn0 = xp[0],  xn1 = xp[16], xn2 = xp[32], xn3 = xp[48];
    float xn4 = xp[64], xn5 = xp[80], xn6 = xp[96];

    for (int d = 0; d < 128; ++d) {
        const bf16x8 bc0 = bn0, bc1 = bn1;
        float xc[7] = {xn0, xn1, xn2, xn3, xn4, xn5, xn6};
        if (d < 127) {                    // 1-deep register prefetch of d+1
            bp0 += 256; bp1 += 256; xp += M_PADX;
            bn0 = *reinterpret_cast<const bf16x8*>(bp0);
            bn1 = *reinterpret_cast<const bf16x8*>(bp1);
            xn0 = xp[0];  xn1 = xp[16]; xn2 = xp[32]; xn3 = xp[48];
            xn4 = xp[64]; xn5 = xp[80]; xn6 = xp[96];
        }
        __builtin_amdgcn_s_setprio(1);
        #pragma unroll
        for (int mt = 0; mt < 7; ++mt) {
            u32x4 au;
            au[0] = cvt_pk_bf16(xc[mt] * hA[mt][0], xc[mt] * hA[mt][1]);
            au[1] = cvt_pk_bf16(xc[mt] * hA[mt][2], xc[mt] * hA[mt][3]);
            au[2] = cvt_pk_bf16(xc[mt] * hB[mt][0], xc[mt] * hB[mt][1]);
            au[3] = cvt_pk_bf16(xc[mt] * hB[mt][2], xc[mt] * hB[mt][3]);
            bf16x8 a = *reinterpret_cast<bf16x8*>(&au);
            acc[mt][0] = __builtin_amdgcn_mfma_f32_16x16x32_bf16(a, bc0, acc[mt][0], 0, 0, 0);
            acc[mt][1] = __builtin_amdgcn_mfma_f32_16x16x32_bf16(a, bc1, acc[mt][1], 0, 0, 0);
        }
        __builtin_amdgcn_s_setprio(0);
    }

    // epilogue: D layout col(o) = lane&15, row(m) = (lane>>4)*4 + reg
    float* outp = Qp + (size_t)kid * M_TOK * DM;
    #pragma unroll
    for (int mt = 0; mt < 7; ++mt)
        #pragma unroll
        for (int r = 0; r < 4; ++r) {
            int m = m0 + mt * 16 + g * 4 + r;
            if (m < M_TOK) {
                float* row = outp + (size_t)m * DM + obase + lr;
                row[0]  = acc[mt][0][r];
                row[16] = acc[mt][1][r];
            }
        }
}

// ---------------- attention + W_out + residual + layernorm ----------------
__global__ __launch_bounds__(256) void k_attn(const float* __restrict__ Qp,
                                              const float* __restrict__ Qb,
                                              const float* __restrict__ Kenc,
                                              const float* __restrict__ Venc,
                                              const float* __restrict__ xin,
                                              const float* __restrict__ Wout,
                                              const float* __restrict__ gamma,
                                              const float* __restrict__ beta,
                                              float* __restrict__ out) {
    __shared__ float Qs[12][132];
    __shared__ float Ks[12][132];
    __shared__ float Vs[12][132];
    __shared__ float Ss[12][12][8];
    __shared__ float Os[12][132];
    __shared__ float Ws[64][132];
    const int t = threadIdx.x;
    const int b = blockIdx.x / NN_;
    const int n = blockIdx.x % NN_;

    for (int e = t; e < 384; e += 256) {
        int row = e >> 5, c4 = e & 31;
        size_t mrow = (size_t)(b * NP + row) * NN_ + n;
        f32x4 q = *reinterpret_cast<const f32x4*>(&Qb[mrow * DM + c4 * 4]);
        #pragma unroll
        for (int k = 0; k < KSPLIT; ++k)
            q += *reinterpret_cast<const f32x4*>(&Qp[((size_t)k * M_TOK + mrow) * DM + c4 * 4]);
        *reinterpret_cast<f32x4*>(&Qs[row][c4 * 4]) = q;
        *reinterpret_cast<f32x4*>(&Ks[row][c4 * 4]) =
            *reinterpret_cast<const f32x4*>(&Kenc[mrow * DM + c4 * 4]);
        *reinterpret_cast<f32x4*>(&Vs[row][c4 * 4]) =
            *reinterpret_cast<const f32x4*>(&Venc[mrow * DM + c4 * 4]);
    }
    __syncthreads();
    if (t < 144) {
        int q = t / 12, p = t % 12;
        #pragma unroll
        for (int hh = 0; hh < 8; ++hh) {
            const f32x4* qv = reinterpret_cast<const f32x4*>(&Qs[q][hh * 16]);
            const f32x4* kv = reinterpret_cast<const f32x4*>(&Ks[p][hh * 16]);
            float s = 0.0f;
            #pragma unroll
            for (int c = 0; c < 4; ++c) {
                f32x4 a = qv[c], bb = kv[c];
                s += a[0] * bb[0] + a[1] * bb[1] + a[2] * bb[2] + a[3] * bb[3];
            }
            Ss[q][p][hh] = s * 0.25f;
        }
    }
    __syncthreads();
    if (t < 96) {
        int q = t >> 3, hh = t & 7;
        float mx = -1e30f;
        #pragma unroll
        for (int p = 0; p < 12; ++p) mx = fmaxf(mx, Ss[q][p][hh]);
        float ev[12]; float sum = 0.0f;
        #pragma unroll
        for (int p = 0; p < 12; ++p) { ev[p] = __expf(Ss[q][p][hh] - mx); sum += ev[p]; }
        float inv = 1.0f / sum;
        #pragma unroll
        for (int p = 0; p < 12; ++p) Ss[q][p][hh] = ev[p] * inv;
    }
    __syncthreads();
    #pragma unroll
    for (int i = 0; i < 6; ++i) {
        int e = i * 256 + t;
        int q = e >> 7, hk = e & 127, hh = hk >> 4;
        float acc = 0.0f;
        #pragma unroll
        for (int p = 0; p < 12; ++p) acc += Ss[q][p][hh] * Vs[p][hk];
        Os[q][hk] = acc;
    }
    __syncthreads();
    for (int half = 0; half < 2; ++half) {
        #pragma unroll
        for (int i = 0; i < 8; ++i) {
            int e = i * 256 + t;
            int row = e >> 5, c4 = e & 31;
            *reinterpret_cast<f32x4*>(&Ws[row][c4 * 4]) =
                *reinterpret_cast<const f32x4*>(&Wout[(size_t)(half * 64 + row) * DM + c4 * 4]);
        }
        __syncthreads();
        #pragma unroll
        for (int i = 0; i < 3; ++i) {
            int idx = i * 256 + t;
            int o = idx / 12, q = idx % 12;
            const f32x4* ov = reinterpret_cast<const f32x4*>(&Os[q][0]);
            const f32x4* wv = reinterpret_cast<const f32x4*>(&Ws[o][0]);
            float s = 0.0f;
            #pragma unroll
            for (int c = 0; c < 32; ++c) {
                f32x4 a = ov[c], bb = wv[c];
                s += a[0] * bb[0] + a[1] * bb[1] + a[2] * bb[2] + a[3] * bb[3];
            }
            int oo = half * 64 + o;
            size_t mrow = (size_t)(b * NP + q) * NN_ + n;
            Qs[q][oo] = s + xin[mrow * DM + oo];
        }
        __syncthreads();
    }
    const int wv_ = t >> 6, l = t & 63;
    for (int rq = wv_; rq < 12; rq += 4) {
        float v0 = Qs[rq][l], v1 = Qs[rq][l + 64];
        float s = v0 + v1, ss = v0 * v0 + v1 * v1;
        #pragma unroll
        for (int msk = 1; msk < 64; msk <<= 1) {
            s += __shfl_xor(s, msk, 64);
            ss += __shfl_xor(ss, msk, 64);
        }
        float mu = s * (1.0f / 128.0f);
        float var = ss * (1.0f / 128.0f) - mu * mu;
        float rs = rsqrtf(var + 1e-5f);
        size_t mrow = (size_t)(b * NP + rq) * NN_ + n;
        out[mrow * DM + l]      = (v0 - mu) * rs * gamma[l] + beta[l];
        out[mrow * DM + l + 64] = (v1 - mu) * rs * gamma[l + 64] + beta[l + 64];
    }
}

// ---------------- launcher ----------------
extern "C" void kernel_launch(void* const* d_in, const int* in_sizes, int n_in,
                              void* d_out, int out_size, void* d_ws, size_t ws_size,
                              hipStream_t stream) {
    const float* xin   = (const float*)d_in[0];
    const float* Kenc  = (const float*)d_in[1];
    const float* Venc  = (const float*)d_in[2];
    const float* ct    = (const float*)d_in[3];
    const float* W1    = (const float*)d_in[4];
    const float* b1    = (const float*)d_in[5];
    const float* W2    = (const float*)d_in[6];
    const float* b2    = (const float*)d_in[7];
    const float* Wout  = (const float*)d_in[8];
    const float* gamma = (const float*)d_in[9];
    const float* beta  = (const float*)d_in[10];
    float* out = (float*)d_out;

    char* ws = (char*)d_ws;
    unsigned short* W2b = (unsigned short*)(ws);                  //  8,388,608 B
    float* xT  = (float*)(ws + 8388608);                          //  5,111,808 B (128 x 9984)
    float* hb  = (float*)(ws + 13500416);                         // 10,174,464 B used
    float* Qb  = (float*)(ws + 23724032);                         //  5,087,232 B used
    float* Qp  = (float*)(ws + 28835840);                         // 40,697,856 B (8 x 9936 x 128)

    hipLaunchKernelGGL(k_prep, dim3(4538), dim3(256), 0, stream,
                       W2, W2b, xin, xT, ct, W1, b1, b2, hb, Qb);
    hipLaunchKernelGGL(k_gemm, dim3(MBLK * KSPLIT), dim3(256), 0, stream, W2b, hb, xT, Qp);
    hipLaunchKernelGGL(k_attn, dim3(828), dim3(256), 0, stream, Qp, Qb, Kenc, Venc,
                       xin, Wout, gamma, beta, out);
}